// Round 1
// baseline (95.478 us; speedup 1.0000x reference)
//
#include <hip/hip_runtime.h>
#include <hip/hip_bf16.h>

// Problem constants
#define N_CONVS 8
#define IN_FEAT 9          // 3x3 patch
#define NCOEF 8            // grid(5) + order(3)
#define NKNOT 12           // grid.shape[1] = 5 + 2*3 + 1
#define HH 64
#define WW 64
#define HO 62
#define WO 62
#define BAND 16            // output rows per block
#define LROWS 18           // input rows per block (BAND + 2)
#define LW 67              // padded LDS row width in pixels (bank-conflict-free)

// cbuf layout in d_ws (floats):
//   [0 .. 647]   W[n][i][j] : j==0 -> base_weight[n][i], j=1..8 -> spline_weight*scaler
//   [648 ..658]  inv1[j] = 1/(g[j+1]-g[j])   (11)
//   [659 ..668]  inv2[j] = 1/(g[j+2]-g[j])   (10)
//   [669 ..677]  inv3[j] = 1/(g[j+3]-g[j])   (9)

__global__ __launch_bounds__(704) void kan_prep(const float* __restrict__ bw,
                                                const float* __restrict__ sw,
                                                const float* __restrict__ sc,
                                                const float* __restrict__ grid,
                                                float* __restrict__ cbuf) {
    int t = threadIdx.x;
    if (t < 648) {
        int j = t % 9, ni = t / 9;
        cbuf[t] = (j == 0) ? bw[ni] : sw[ni * 8 + (j - 1)] * sc[ni];
    } else if (t < 659) {
        int j = t - 648; cbuf[t] = 1.0f / (grid[j + 1] - grid[j]);
    } else if (t < 669) {
        int j = t - 659; cbuf[t] = 1.0f / (grid[j + 2] - grid[j]);
    } else if (t < 678) {
        int j = t - 669; cbuf[t] = 1.0f / (grid[j + 3] - grid[j]);
    }
}

__global__ __launch_bounds__(256, 3) void kan_main(const float* __restrict__ x,
                                                   const float* __restrict__ grid,
                                                   const float* __restrict__ cbuf,
                                                   float* __restrict__ out) {
    __shared__ float feat[LROWS * LW * 9];

    const int blk  = blockIdx.x;
    const int band = blk & 3;
    const int img  = blk >> 2;             // b*32 + c, 0..255
    const int r0   = band * BAND;
    const int nr       = (HO - r0) < BAND ? (HO - r0) : BAND;     // 16,16,16,14
    const int nrows_in = (HH - r0) < LROWS ? (HH - r0) : LROWS;   // 18,18,18,16

    // Uniform constants -> scalar loads
    float g[NKNOT];
#pragma unroll
    for (int j = 0; j < NKNOT; j++) g[j] = grid[j];
    float i1[11], i2[10], i3[9];
#pragma unroll
    for (int j = 0; j < 11; j++) i1[j] = cbuf[648 + j];
#pragma unroll
    for (int j = 0; j < 10; j++) i2[j] = cbuf[659 + j];
#pragma unroll
    for (int j = 0; j < 9; j++)  i3[j] = cbuf[669 + j];

    // ---- Phase 1: per-pixel features into LDS ----
    const float* xb = x + (size_t)img * (HH * WW) + (size_t)r0 * WW;
    for (int p = threadIdx.x; p < nrows_in * WW; p += 256) {
        const int r = p >> 6, c = p & 63;
        const float xv = xb[r * WW + c];

        const float sg = 1.0f / (1.0f + expf(-xv));   // sigmoid
        const float s0 = xv * sg;                     // silu

        float ee[12], d[12];
#pragma unroll
        for (int j = 0; j < 12; j++) {
            ee[j] = xv - g[j];
            d[j]  = (xv >= g[j]) ? 1.0f : 0.0f;
        }
        float b0[11];
#pragma unroll
        for (int j = 0; j < 11; j++) b0[j] = d[j] - d[j + 1];   // indicator of [g_j, g_{j+1})
        float b1[10];
#pragma unroll
        for (int j = 0; j < 10; j++)
            b1[j] = (ee[j] * i1[j]) * b0[j] - (ee[j + 2] * i1[j + 1]) * b0[j + 1];
        float b2[9];
#pragma unroll
        for (int j = 0; j < 9; j++)
            b2[j] = (ee[j] * i2[j]) * b1[j] - (ee[j + 3] * i2[j + 1]) * b1[j + 1];
        float b3[8];
#pragma unroll
        for (int j = 0; j < 8; j++)
            b3[j] = (ee[j] * i3[j]) * b2[j] - (ee[j + 4] * i3[j + 1]) * b2[j + 1];

        float* f = &feat[(r * LW + c) * 9];
        f[0] = s0;
#pragma unroll
        for (int j = 0; j < 8; j++) f[j + 1] = b3[j];
    }
    __syncthreads();

    // ---- Phase 2: 4 output pixels (one row, consecutive x) for all 8 convs ----
    const int row = threadIdx.x >> 4;
    const int xs  = (threadIdx.x & 15) * 4;
    if (row < nr) {
        float acc[N_CONVS][4];
#pragma unroll
        for (int n = 0; n < N_CONVS; n++)
#pragma unroll
            for (int t = 0; t < 4; t++) acc[n][t] = 0.0f;

#pragma unroll 1
        for (int ky = 0; ky < 3; ky++) {
            float fw[6][9];
#pragma unroll
            for (int c6 = 0; c6 < 6; c6++) {
                const float* fp = &feat[((row + ky) * LW + xs + c6) * 9];
#pragma unroll
                for (int j = 0; j < 9; j++) fw[c6][j] = fp[j];
            }
#pragma unroll
            for (int kx = 0; kx < 3; kx++) {
#pragma unroll
                for (int n = 0; n < N_CONVS; n++) {
#pragma unroll
                    for (int j = 0; j < 9; j++) {
                        const float w = cbuf[((n * 9) + (ky * 3 + kx)) * 9 + j];
#pragma unroll
                        for (int t = 0; t < 4; t++)
                            acc[n][t] = fmaf(fw[kx + t][j], w, acc[n][t]);
                    }
                }
            }
        }

        const int oy = r0 + row;
        float* ob = out + ((size_t)img * N_CONVS) * (HO * WO) + oy * WO + xs;
#pragma unroll
        for (int n = 0; n < N_CONVS; n++) {
            float* o = ob + n * (HO * WO);
            *(float2*)o = make_float2(acc[n][0], acc[n][1]);
            if (xs < 58) *(float2*)(o + 2) = make_float2(acc[n][2], acc[n][3]);
        }
    }
}

extern "C" void kernel_launch(void* const* d_in, const int* in_sizes, int n_in,
                              void* d_out, int out_size, void* d_ws, size_t ws_size,
                              hipStream_t stream) {
    const float* x    = (const float*)d_in[0];
    const float* bw   = (const float*)d_in[1];
    const float* sw   = (const float*)d_in[2];
    const float* sc   = (const float*)d_in[3];
    const float* grid = (const float*)d_in[4];
    float* out  = (float*)d_out;
    float* cbuf = (float*)d_ws;

    kan_prep<<<1, 704, 0, stream>>>(bw, sw, sc, grid, cbuf);
    kan_main<<<256 * 4, 256, 0, stream>>>(x, grid, cbuf, out);
}

// Round 2
// 95.466 us; speedup vs baseline: 1.0001x; 1.0001x over previous
//
#include <hip/hip_runtime.h>
#include <hip/hip_bf16.h>

// KAN conv layer: 8 independent KANLinear(9->1) convs over 3x3 patches.
// Features (silu + 8 cubic B-spline basis values) depend only on the PIXEL
// value -> compute once per pixel into LDS (phase 1), then per-patch dense
// dot products with wave-uniform (SGPR) weights (phase 2).
//
// Geometry: 1024 blocks = 256 (b*32+c images) x 4 row-bands of 16 output
// rows; 256 threads. LDS feat[18 rows][65 cols][9 f32] = 42.1 KB -> 3
// blocks/CU. LW=65: phase-2 read banks = (585r+36j+9c6)%32 -> disjoint per
// row-group -> 2 lanes/bank = free (m136). Single dispatch, no d_ws.

#define N_CONVS 8
#define HH 64
#define WW 64
#define HO 62
#define WO 62
#define BAND 16
#define LROWS 18
#define LW 65

__global__ __launch_bounds__(256, 3) void kan_fused(
    const float* __restrict__ x,     // [8,32,64,64]
    const float* __restrict__ bw,    // [8][9]
    const float* __restrict__ sw,    // [8][9][8]
    const float* __restrict__ sc,    // [8][9]
    const float* __restrict__ grid,  // [9][12], rows identical
    float* __restrict__ out)         // [8,32*8,62,62]
{
    __shared__ float feat[LROWS * LW * 9];

    const int blk  = blockIdx.x;
    const int band = blk & 3;
    const int img  = blk >> 2;                                   // b*32+c
    const int r0   = band * BAND;
    const int nr   = (HO - r0) < BAND ? (HO - r0) : BAND;        // 16,16,16,14
    const int nin  = (HH - r0) < LROWS ? (HH - r0) : LROWS;      // 18,18,18,16

    // Uniform knot values + folded reciprocals (hw rcp, ~1 ulp; tolerance
    // headroom per R0 absmax=0.0156 passing).
    float g[12];
#pragma unroll
    for (int j = 0; j < 12; j++) g[j] = grid[j];
    float i1[11], i2[10], i3[9];
#pragma unroll
    for (int j = 0; j < 11; j++) i1[j] = __builtin_amdgcn_rcpf(g[j + 1] - g[j]);
#pragma unroll
    for (int j = 0; j < 10; j++) i2[j] = __builtin_amdgcn_rcpf(g[j + 2] - g[j]);
#pragma unroll
    for (int j = 0; j < 9; j++)  i3[j] = __builtin_amdgcn_rcpf(g[j + 3] - g[j]);

    // ---- Phase 1: per-pixel features into LDS ----
    const float* xb = x + (size_t)img * (HH * WW) + (size_t)r0 * WW;
    for (int p = threadIdx.x; p < nin * WW; p += 256) {
        const int r = p >> 6, c = p & 63;
        const float xv = xb[p];                       // rows contiguous

        const float s0 = xv * __builtin_amdgcn_rcpf(1.0f + __expf(-xv));

        float ee[12], d[12];
#pragma unroll
        for (int j = 0; j < 12; j++) {
            ee[j] = xv - g[j];
            d[j]  = (xv >= g[j]) ? 1.0f : 0.0f;
        }
        float b0[11];
#pragma unroll
        for (int j = 0; j < 11; j++) b0[j] = d[j] - d[j + 1];
        float b1[10];
#pragma unroll
        for (int j = 0; j < 10; j++)
            b1[j] = (ee[j] * i1[j]) * b0[j] - (ee[j + 2] * i1[j + 1]) * b0[j + 1];
        float b2[9];
#pragma unroll
        for (int j = 0; j < 9; j++)
            b2[j] = (ee[j] * i2[j]) * b1[j] - (ee[j + 3] * i2[j + 1]) * b1[j + 1];
        float b3[8];
#pragma unroll
        for (int j = 0; j < 8; j++)
            b3[j] = (ee[j] * i3[j]) * b2[j] - (ee[j + 4] * i3[j + 1]) * b2[j + 1];

        float* f = &feat[(r * LW + c) * 9];
        f[0] = s0;
#pragma unroll
        for (int j = 0; j < 8; j++) f[j + 1] = b3[j];
    }
    __syncthreads();

    // ---- Phase 2: 4 consecutive output cols x 8 convs per thread ----
    const int row = threadIdx.x >> 4;
    const int xs  = (threadIdx.x & 15) * 4;
    if (row < nr) {
        float acc[N_CONVS][4];
#pragma unroll
        for (int n = 0; n < N_CONVS; n++)
#pragma unroll
            for (int t = 0; t < 4; t++) acc[n][t] = 0.0f;

#pragma unroll 1
        for (int ky = 0; ky < 3; ky++) {
            float fw[6][9];
#pragma unroll
            for (int c6 = 0; c6 < 6; c6++) {
                const float* fp = &feat[((row + ky) * LW + xs + c6) * 9];
#pragma unroll
                for (int j = 0; j < 9; j++) fw[c6][j] = fp[j];
            }
#pragma unroll
            for (int kx = 0; kx < 3; kx++) {
                const int i = ky * 3 + kx;
#pragma unroll
                for (int n = 0; n < N_CONVS; n++) {
                    const float scv = sc[n * 9 + i];     // s_load (uniform)
                    const float bwv = bw[n * 9 + i];
                    const float* swp = sw + ((n * 9 + i) << 3);
                    float s[4];
#pragma unroll
                    for (int t = 0; t < 4; t++) s[t] = swp[0] * fw[kx + t][1];
#pragma unroll
                    for (int j = 1; j < 8; j++) {
                        const float w = swp[j];
#pragma unroll
                        for (int t = 0; t < 4; t++)
                            s[t] = fmaf(w, fw[kx + t][j + 1], s[t]);
                    }
#pragma unroll
                    for (int t = 0; t < 4; t++) {
                        acc[n][t] = fmaf(scv, s[t], acc[n][t]);
                        acc[n][t] = fmaf(bwv, fw[kx + t][0], acc[n][t]);
                    }
                }
            }
        }

        const int oy = r0 + row;
        float* ob = out + (size_t)img * N_CONVS * (HO * WO) + oy * WO + xs;
#pragma unroll
        for (int n = 0; n < N_CONVS; n++) {
            float* o = ob + n * (HO * WO);
            *(float2*)o = make_float2(acc[n][0], acc[n][1]);
            if (xs < 58) *(float2*)(o + 2) = make_float2(acc[n][2], acc[n][3]);
        }
    }
}

extern "C" void kernel_launch(void* const* d_in, const int* in_sizes, int n_in,
                              void* d_out, int out_size, void* d_ws, size_t ws_size,
                              hipStream_t stream) {
    const float* x    = (const float*)d_in[0];
    const float* bw   = (const float*)d_in[1];
    const float* sw   = (const float*)d_in[2];
    const float* sc   = (const float*)d_in[3];
    const float* grid = (const float*)d_in[4];
    float* out = (float*)d_out;

    kan_fused<<<256 * 4, 256, 0, stream>>>(x, bw, sw, sc, grid, out);
}